// Round 5
// baseline (585.288 us; speedup 1.0000x reference)
//
#include <hip/hip_runtime.h>
#include <cstddef>

typedef __attribute__((ext_vector_type(8))) short short8;
typedef __attribute__((ext_vector_type(4))) float f32x4;

#define WC_CONST 0.2357022603955158f   // sqrt(2/(9*4))
#define WL_CONST 0.5773502691896258f   // sqrt(1/3)

__device__ __forceinline__ unsigned short rne_bf16(float f) {
  unsigned int u = __float_as_uint(f);
  u += 0x7fffu + ((u >> 16) & 1u);
  return (unsigned short)(u >> 16);
}

typedef const __attribute__((address_space(1))) unsigned int* gas_u32;
typedef __attribute__((address_space(3))) unsigned int* las_u32;

// async global->LDS, 16B per lane: lds dest = uniform base + lane*16
__device__ __forceinline__ void gl_lds16(const float* g, float* l) {
  __builtin_amdgcn_global_load_lds((gas_u32)(const void*)g, (las_u32)(void*)l, 16, 0, 0);
}

// ---------------- concat projection weights into [384][1152] ----------------
__global__ __launch_bounds__(256) void concat_w_kernel(
    const float* __restrict__ Wq, const float* __restrict__ Wk, const float* __restrict__ Wv,
    const float* __restrict__ Wqp, const float* __restrict__ Wkp, const float* __restrict__ Wvp,
    float* __restrict__ Wcat) {
  int idx = blockIdx.x * 256 + threadIdx.x;
  if (idx >= 384 * 1152) return;
  int k = idx / 1152, c = idx % 1152;
  float v;
  if (c < 192)       v = Wq [k*192 + c];
  else if (c < 384)  v = Wk [k*192 + (c-192)];
  else if (c < 576)  v = Wv [k*192 + (c-384)];
  else if (c < 720)  v = Wqp[k*144 + (c-576)];
  else if (c < 864)  v = Wkp[k*144 + (c-720)];
  else               v = Wvp[k*288 + (c-864)];
  Wcat[idx] = v;
}

// ---------------- generic fp32 tiled GEMM, 64x64 tile, split-K ----------------
__global__ __launch_bounds__(256) void gemm64_kernel(
    const float* __restrict__ Amat, const float* __restrict__ Bmat, float* __restrict__ Cp,
    int M, int N, int K, int ksl) {
  __shared__ float As[16][68];
  __shared__ float Bs[16][68];
  int t = threadIdx.x;
  int bn = blockIdx.x, bm = blockIdx.y, bz = blockIdx.z;
  int k0 = bz * ksl;
  int tr = t >> 4, tc = t & 15;
  int lm = t >> 2, lk4 = (t & 3) << 2;
  int lkb = t >> 4, lnq = (t & 15) << 2;
  const float* Ab = Amat + (size_t)(bm*64 + lm) * K;
  const float* Bb = Bmat + bn*64 + lnq;
  float acc[4][4];
  #pragma unroll
  for (int a2 = 0; a2 < 4; a2++)
    #pragma unroll
    for (int b2 = 0; b2 < 4; b2++) acc[a2][b2] = 0.f;

  for (int k = k0; k < k0 + ksl; k += 16) {
    float4 av = *(const float4*)(Ab + k + lk4);
    float4 bv = *(const float4*)(Bb + (size_t)(k + lkb) * N);
    As[lk4+0][lm] = av.x; As[lk4+1][lm] = av.y; As[lk4+2][lm] = av.z; As[lk4+3][lm] = av.w;
    *(float4*)&Bs[lkb][lnq] = bv;
    __syncthreads();
    #pragma unroll
    for (int kk = 0; kk < 16; kk++) {
      float4 a4 = *(const float4*)&As[kk][tr << 2];
      float4 b4 = *(const float4*)&Bs[kk][tc << 2];
      float ar[4] = {a4.x, a4.y, a4.z, a4.w};
      float br[4] = {b4.x, b4.y, b4.z, b4.w};
      #pragma unroll
      for (int a2 = 0; a2 < 4; a2++)
        #pragma unroll
        for (int b2 = 0; b2 < 4; b2++) acc[a2][b2] += ar[a2] * br[b2];
    }
    __syncthreads();
  }
  float* Cb = Cp + (size_t)bz * M * N + (size_t)(bm*64 + (tr << 2)) * N + bn*64 + (tc << 2);
  #pragma unroll
  for (int r = 0; r < 4; r++) {
    float4 o = {acc[r][0], acc[r][1], acc[r][2], acc[r][3]};
    *(float4*)(Cb + (size_t)r * N) = o;
  }
}

// ---------------- split-K reduce ----------------
__global__ __launch_bounds__(256) void reduce_kernel(
    const float* __restrict__ Cp, float* __restrict__ out, const float* __restrict__ bias,
    int relu, int MN, int N, int sk) {
  int idx = blockIdx.x * 256 + threadIdx.x;
  if (idx >= MN) return;
  float s = 0.f;
  for (int z = 0; z < sk; z++) s += Cp[(size_t)z * MN + idx];
  if (bias) s += bias[idx % N];
  if (relu) s = fmaxf(s, 0.f);
  out[idx] = s;
}

// ---------------- 32x32-tile GEMM, fused bias/relu, no split-K ------
__global__ __launch_bounds__(256) void gemm32_kernel(
    const float* __restrict__ Amat, const float* __restrict__ Bmat,
    const float* __restrict__ bias,
    float* __restrict__ C, int M, int N, int K, int relu) {
  __shared__ float As[16][34];
  __shared__ float Bs[16][34];
  int t = threadIdx.x;
  int bn = blockIdx.x, bm = blockIdx.y;
  int tr = t >> 4, tc = t & 15;
  int lm = t >> 3, lk2 = (t & 7) << 1;
  int lkb = t >> 4, ln2 = (t & 15) << 1;
  const float* Ab = Amat + (size_t)(bm*32 + lm) * K;
  const float* Bb = Bmat + bn*32 + ln2;
  float a00=0.f, a01=0.f, a10=0.f, a11=0.f;
  for (int k = 0; k < K; k += 16) {
    float2 av = *(const float2*)(Ab + k + lk2);
    float2 bv = *(const float2*)(Bb + (size_t)(k + lkb) * N);
    As[lk2][lm] = av.x; As[lk2+1][lm] = av.y;
    *(float2*)&Bs[lkb][ln2] = bv;
    __syncthreads();
    #pragma unroll
    for (int kk = 0; kk < 16; kk++) {
      float2 a2 = *(const float2*)&As[kk][tr << 1];
      float2 b2 = *(const float2*)&Bs[kk][tc << 1];
      a00 += a2.x*b2.x; a01 += a2.x*b2.y; a10 += a2.y*b2.x; a11 += a2.y*b2.y;
    }
    __syncthreads();
  }
  int r0 = bm*32 + (tr << 1), c0 = bn*32 + (tc << 1);
  float bb0 = bias ? bias[c0] : 0.f, bb1 = bias ? bias[c0+1] : 0.f;
  float o00 = a00 + bb0, o01 = a01 + bb1, o10 = a10 + bb0, o11 = a11 + bb1;
  if (relu) { o00=fmaxf(o00,0.f); o01=fmaxf(o01,0.f); o10=fmaxf(o10,0.f); o11=fmaxf(o11,0.f); }
  float2 w0 = {o00, o01}, w1 = {o10, o11};
  *(float2*)(C + (size_t)r0*N + c0) = w0;
  *(float2*)(C + (size_t)(r0+1)*N + c0) = w1;
}

// ---------------- frames ----------------
__global__ __launch_bounds__(64) void frames_kernel(
    const float* __restrict__ proj, const float* __restrict__ quat, const float* __restrict__ trsl,
    float* __restrict__ rotb, float* __restrict__ qpg, float* __restrict__ kpg,
    float* __restrict__ vpg) {
  int i = blockIdx.x, t = threadIdx.x;
  float q0 = quat[i*3+0], q1 = quat[i*3+1], q2 = quat[i*3+2];
  float inv = rsqrtf(1.f + q0*q0 + q1*q1 + q2*q2);
  float w = inv, x = q0*inv, y = q1*inv, z = q2*inv;
  float R00 = 1.f - 2.f*(y*y + z*z), R01 = 2.f*(x*y - w*z), R02 = 2.f*(x*z + w*y);
  float R10 = 2.f*(x*y + w*z), R11 = 1.f - 2.f*(x*x + z*z), R12 = 2.f*(y*z - w*x);
  float R20 = 2.f*(x*z - w*y), R21 = 2.f*(y*z + w*x), R22 = 1.f - 2.f*(x*x + y*y);
  float t0 = trsl[i*3+0], t1 = trsl[i*3+1], t2 = trsl[i*3+2];
  if (t == 0) {
    float* rb = rotb + i*9;
    rb[0]=R00; rb[1]=R01; rb[2]=R02; rb[3]=R10; rb[4]=R11; rb[5]=R12; rb[6]=R20; rb[7]=R21; rb[8]=R22;
  }
  for (int pt = t; pt < 192; pt += 64) {
    const float* src; float* dst;
    if (pt < 48)      { src = proj + i*1152 + 576 + pt*3;        dst = qpg + i*144 + pt*3; }
    else if (pt < 96) { src = proj + i*1152 + 720 + (pt-48)*3;   dst = kpg + i*144 + (pt-48)*3; }
    else              { src = proj + i*1152 + 864 + (pt-96)*3;   dst = vpg + i*288 + (pt-96)*3; }
    float p0 = src[0], p1 = src[1], p2 = src[2];
    dst[0] = R00*p0 + R01*p1 + R02*p2 + t0;
    dst[1] = R10*p0 + R11*p1 + R12*p2 + t1;
    dst[2] = R20*p0 + R21*p1 + R22*p2 + t2;
  }
}

// ---------------- logit (qk/4 - coef*d2) ----------------
__device__ __forceinline__ float lt1_val(
    const float* __restrict__ proj, const float* __restrict__ kpg,
    const float* qs_, const float* qps_, float coef, int jg, int h) {
  const float4* kr = (const float4*)(proj + (size_t)jg*1152 + 192 + h*16);
  const float4* qr = (const float4*)(qs_ + h*16);
  float qk = 0.f;
  #pragma unroll
  for (int m = 0; m < 4; m++) {
    float4 kv = kr[m], qv = qr[m];
    qk += qv.x*kv.x + qv.y*kv.y + qv.z*kv.z + qv.w*kv.w;
  }
  const float4* kpr = (const float4*)(kpg + (size_t)jg*144 + h*12);
  const float4* qpr = (const float4*)(qps_ + h*12);
  float d2 = 0.f;
  #pragma unroll
  for (int m = 0; m < 3; m++) {
    float4 kv = kpr[m], qv = qpr[m];
    float dx = qv.x-kv.x, dy = qv.y-kv.y, dz = qv.z-kv.z, dw = qv.w-kv.w;
    d2 += dx*dx + dy*dy + dz*dz + dw*dw;
  }
  return qk*0.25f - coef*d2;
}

// ---------------- fused single-pass attention, gload_lds pipeline ------------
// 768 thr = 12 waves. Per 16-row subtile:
//  A: w0 b-MFMA+exp->Lw | w1-3 logits(t+1) | w4-7 issue gload_lds(t+1)
//  rawB (lgkm only, loads stay in flight)
//  C: w0-5 op | w6-9 ov | w10-11 ovp_g
//  E: __syncthreads (drains vmcnt -> next P visible)
__global__ __launch_bounds__(768, 6) void attn3_kernel(
    const float* __restrict__ proj, const float* __restrict__ qpg,
    const float* __restrict__ kpg, const float* __restrict__ vpg,
    const float* __restrict__ pfea, const float* __restrict__ Wb,
    const float* __restrict__ rotb, const float* __restrict__ trsl,
    const float* __restrict__ scale, float* __restrict__ shid) {
  __shared__ __align__(16) float P[2][16][260];
  __shared__ __align__(16) float Lw[512][12];
  __shared__ short wbf[8][64][8];
  __shared__ float Lb[2][16][12];
  __shared__ __align__(16) float qs[12][16];
  __shared__ __align__(16) float qps[12][12];
  __shared__ float coefs[12], sh_inv[12], rot_s[9];
  __shared__ __align__(16) float redbuf[2048];
  __shared__ float ovpg_l[12][24];

  int i = blockIdx.x, t = threadIdx.x;
  int w = t >> 6, lane = t & 63;

  for (int idx = t; idx < 192; idx += 768) qs[idx >> 4][idx & 15] = proj[i*1152 + idx];
  for (int idx = t; idx < 144; idx += 768) qps[idx / 12][idx % 12] = qpg[i*144 + idx];
  if (t < 12) coefs[t] = WC_CONST * 0.5f * log1pf(__expf(scale[t]));
  if (t < 9)  rot_s[t] = rotb[i*9 + t];
  for (int s2 = t; s2 < 512; s2 += 768) {
    int ks = s2 >> 6, l = s2 & 63;
    int col = l & 15, kb = ks * 32 + ((l >> 4) << 3);
    #pragma unroll
    for (int j = 0; j < 8; j++)
      wbf[ks][l][j] = (col < 12) ? (short)rne_bf16(Wb[(kb + j) * 12 + col]) : (short)0;
  }
  __syncthreads();

  // prologue: logits(0) + stage ST0
  if (w >= 1 && w <= 3) {
    int e = (w - 1) * 64 + lane;
    int jl = e / 12, h = e - jl * 12;
    Lb[0][jl][h] = lt1_val(proj, kpg, &qs[0][0], &qps[0][0], coefs[h], jl, h);
  } else if (w >= 4 && w <= 7) {
    int r = (w - 4) * 4;
    const float* src = pfea + (size_t)i * 131072 + lane * 4;
    #pragma unroll
    for (int q = 0; q < 4; q++) gl_lds16(src + (size_t)(r + q) * 256, &P[0][r + q][0]);
  }
  __syncthreads();   // drains vmcnt: P[0] ready, Lb[0] ready

  float4 acc4[4];
  #pragma unroll
  for (int c = 0; c < 4; c++) { acc4[c].x=0.f; acc4[c].y=0.f; acc4[c].z=0.f; acc4[c].w=0.f; }
  float accv[3] = {0.f, 0.f, 0.f};
  float accvp[5] = {0.f, 0.f, 0.f, 0.f, 0.f};
  int hv0 = lane >> 4, hv1 = 4 + (lane >> 4), hv2 = 8 + (lane >> 4);
  int hp0 = lane / 24, hp1 = (lane + 64) / 24, hp2 = (lane + 128) / 24,
      hp3 = (lane + 192) / 24, hp4 = (lane + 256) / 24;

  int cur = 0;
  for (int tt = 0; tt < 32; tt++) {
    // ---- phase A ----
    if (w == 0) {
      f32x4 accb = {0.f, 0.f, 0.f, 0.f};
      int row = lane & 15, kq = lane >> 4;
      const float* Pb = &P[cur][row][kq * 8];
      #pragma unroll
      for (int ks = 0; ks < 8; ks++) {
        float4 f0 = *(const float4*)(Pb + ks * 32);
        float4 f1 = *(const float4*)(Pb + ks * 32 + 4);
        short8 af;
        af[0] = (short)rne_bf16(f0.x); af[1] = (short)rne_bf16(f0.y);
        af[2] = (short)rne_bf16(f0.z); af[3] = (short)rne_bf16(f0.w);
        af[4] = (short)rne_bf16(f1.x); af[5] = (short)rne_bf16(f1.y);
        af[6] = (short)rne_bf16(f1.z); af[7] = (short)rne_bf16(f1.w);
        short8 bfv = *(const short8*)(&wbf[ks][lane][0]);
        accb = __builtin_amdgcn_mfma_f32_16x16x32_bf16(af, bfv, accb, 0, 0, 0);
      }
      int h = lane & 15;
      if (h < 12) {
        #pragma unroll
        for (int r = 0; r < 4; r++) {
          int jl = kq * 4 + r;
          Lw[tt * 16 + jl][h] = __expf(WL_CONST * (Lb[tt & 1][jl][h] + accb[r]));
        }
      }
    } else if (w <= 3) {
      if (tt < 31) {
        int e = (w - 1) * 64 + lane;
        int jl = e / 12, h = e - jl * 12;
        Lb[(tt + 1) & 1][jl][h] =
            lt1_val(proj, kpg, &qs[0][0], &qps[0][0], coefs[h], (tt + 1) * 16 + jl, h);
      }
    } else if (w <= 7) {
      if (tt < 31) {
        int r = (w - 4) * 4;
        const float* src = pfea + (size_t)i * 131072 + (size_t)(tt + 1) * 4096 + lane * 4;
        #pragma unroll
        for (int q = 0; q < 4; q++) gl_lds16(src + (size_t)(r + q) * 256, &P[cur ^ 1][r + q][0]);
      }
    }
    // ---- raw barrier B: order LDS, keep global_load_lds in flight ----
    asm volatile("s_waitcnt lgkmcnt(0)" ::: "memory");
    __builtin_amdgcn_sched_barrier(0);
    __builtin_amdgcn_s_barrier();
    __builtin_amdgcn_sched_barrier(0);
    // ---- phase C ----
    if (w < 6) {
      int qd = w >> 1, rp = w & 1;
      #pragma unroll
      for (int r = 0; r < 16; r += 2) {
        int rr = r + rp;
        float4 lq = *(const float4*)&Lw[tt * 16 + rr][qd * 4];
        float4 pv = *(const float4*)&P[cur][rr][lane << 2];
        acc4[0].x += pv.x*lq.x; acc4[0].y += pv.y*lq.x; acc4[0].z += pv.z*lq.x; acc4[0].w += pv.w*lq.x;
        acc4[1].x += pv.x*lq.y; acc4[1].y += pv.y*lq.y; acc4[1].z += pv.z*lq.y; acc4[1].w += pv.w*lq.y;
        acc4[2].x += pv.x*lq.z; acc4[2].y += pv.y*lq.z; acc4[2].z += pv.z*lq.z; acc4[2].w += pv.w*lq.z;
        acc4[3].x += pv.x*lq.w; acc4[3].y += pv.y*lq.w; acc4[3].z += pv.z*lq.w; acc4[3].w += pv.w*lq.w;
      }
    } else if (w < 10) {
      #pragma unroll
      for (int q = 0; q < 4; q++) {
        int j = tt * 16 + (w - 6) * 4 + q;
        const float* vrow = proj + (size_t)j * 1152 + 384;
        accv[0] += Lw[j][hv0] * vrow[lane];
        accv[1] += Lw[j][hv1] * vrow[64 + lane];
        accv[2] += Lw[j][hv2] * vrow[128 + lane];
      }
    } else {
      #pragma unroll
      for (int q = 0; q < 8; q++) {
        int j = tt * 16 + (w - 10) * 8 + q;
        const float* vprow = vpg + (size_t)j * 288;
        accvp[0] += Lw[j][hp0] * vprow[lane];
        accvp[1] += Lw[j][hp1] * vprow[64 + lane];
        accvp[2] += Lw[j][hp2] * vprow[128 + lane];
        accvp[3] += Lw[j][hp3] * vprow[192 + lane];
        if (lane < 32) accvp[4] += Lw[j][hp4] * vprow[256 + lane];
      }
    }
    __syncthreads();   // E: drains vmcnt -> P[cur^1] visible; P[cur] free
    cur ^= 1;
  }

  // ---- sh_inv ----
  {
    float sacc = 0.f;
    #pragma unroll
    for (int r2 = 0; r2 < 8; r2++) sacc += Lw[lane + 64 * r2][w];
    #pragma unroll
    for (int off = 32; off >= 1; off >>= 1) sacc += __shfl_xor(sacc, off);
    if (lane == 0 && w < 12) sh_inv[w] = 1.0f / sacc;
  }
  __syncthreads();

  // ---- op reduce: 3 rounds (one head-quad each) ----
  float4* rb4 = (float4*)redbuf;
  #pragma unroll
  for (int qd2 = 0; qd2 < 3; qd2++) {
    if (w < 6 && (w >> 1) == qd2) {
      int half = w & 1;
      #pragma unroll
      for (int c = 0; c < 4; c++) rb4[half * 256 + c * 64 + lane] = acc4[c];
    }
    __syncthreads();
    if (t < 256) {
      int c = t >> 6, ll = t & 63;
      float4 s0 = rb4[c * 64 + ll], s1 = rb4[256 + c * 64 + ll];
      int h = qd2 * 4 + c;
      float isv = sh_inv[h];
      float4 o = {(s0.x + s1.x) * isv, (s0.y + s1.y) * isv,
                  (s0.z + s1.z) * isv, (s0.w + s1.w) * isv};
      *(float4*)(shid + (size_t)i * 3648 + h * 304 + (ll << 2)) = o;
    }
    __syncthreads();
  }

  // ---- ov / ovp_g reduce ----
  if (w >= 6 && w < 10) {
    int sl = w - 6;
    redbuf[sl * 192 + lane]       = accv[0];
    redbuf[sl * 192 + 64 + lane]  = accv[1];
    redbuf[sl * 192 + 128 + lane] = accv[2];
  } else if (w >= 10) {
    int sl = w - 10;
    #pragma unroll
    for (int k = 0; k < 4; k++) redbuf[768 + sl * 288 + lane + 64 * k] = accvp[k];
    if (lane < 32) redbuf[768 + sl * 288 + 256 + lane] = accvp[4];
  }
  __syncthreads();
  if (t < 192) {
    int h = t >> 4;
    float s = (redbuf[t] + redbuf[192 + t] + redbuf[384 + t] + redbuf[576 + t]) * sh_inv[h];
    shid[(size_t)i * 3648 + h * 304 + 256 + (t & 15)] = s;
  } else if (t >= 256 && t < 544) {
    int m = t - 256, h = m / 24;
    float s = (redbuf[768 + m] + redbuf[768 + 288 + m]) * sh_inv[h];
    ovpg_l[h][m - h * 24] = s;
  }
  __syncthreads();

  if (t < 96) {
    int h = t >> 3, vv = t & 7;
    float x = ovpg_l[h][vv*3+0] - trsl[i*3+0];
    float y = ovpg_l[h][vv*3+1] - trsl[i*3+1];
    float z = ovpg_l[h][vv*3+2] - trsl[i*3+2];
    float o0 = rot_s[0]*x + rot_s[3]*y + rot_s[6]*z;
    float o1 = rot_s[1]*x + rot_s[4]*y + rot_s[7]*z;
    float o2 = rot_s[2]*x + rot_s[5]*y + rot_s[8]*z;
    float* so = shid + (size_t)i*3648 + h*304 + 272 + vv*3;
    so[0] = o0; so[1] = o1; so[2] = o2;
    shid[(size_t)i*3648 + h*304 + 296 + vv] = sqrtf(o0*o0 + o1*o1 + o2*o2);
  }
}

// ---------------- LayerNorm over 384 ----------------
__global__ __launch_bounds__(384) void ln384_kernel(
    const float* __restrict__ resid, const float* __restrict__ C, const float* __restrict__ bias,
    const float* __restrict__ g, const float* __restrict__ be, float* __restrict__ out) {
  int i = blockIdx.x, t = threadIdx.x;
  __shared__ float red[6];
  float x = resid[(size_t)i*384 + t] + C[(size_t)i*384 + t] + bias[t];
  float s = x;
  #pragma unroll
  for (int off = 32; off >= 1; off >>= 1) s += __shfl_xor(s, off);
  if ((t & 63) == 0) red[t >> 6] = s;
  __syncthreads();
  float m = (red[0]+red[1]+red[2]+red[3]+red[4]+red[5]) * (1.f/384.f);
  __syncthreads();
  float d = x - m;
  float v = d * d;
  #pragma unroll
  for (int off = 32; off >= 1; off >>= 1) v += __shfl_xor(v, off);
  if ((t & 63) == 0) red[t >> 6] = v;
  __syncthreads();
  float var = (red[0]+red[1]+red[2]+red[3]+red[4]+red[5]) * (1.f/384.f);
  out[(size_t)i*384 + t] = d * rsqrtf(var + 1e-5f) * g[t] + be[t];
}

// ---------------- launcher ----------------
extern "C" void kernel_launch(void* const* d_in, const int* in_sizes, int n_in,
                              void* d_out, int out_size, void* d_ws, size_t ws_size,
                              hipStream_t stream) {
  const float* sfea = (const float*)d_in[0];
  const float* pfea = (const float*)d_in[1];
  const float* quat = (const float*)d_in[2];
  const float* trsl = (const float*)d_in[3];
  const float* Wq   = (const float*)d_in[4];
  const float* Wk   = (const float*)d_in[5];
  const float* Wv   = (const float*)d_in[6];
  const float* Wqp  = (const float*)d_in[7];
  const float* Wkp  = (const float*)d_in[8];
  const float* Wvp  = (const float*)d_in[9];
  const float* Wb   = (const float*)d_in[10];
  const float* scale= (const float*)d_in[11];
  const float* Wsm  = (const float*)d_in[12];
  const float* bs   = (const float*)d_in[13];
  const float* W1   = (const float*)d_in[14];
  const float* b1   = (const float*)d_in[15];
  const float* W2   = (const float*)d_in[16];
  const float* b2   = (const float*)d_in[17];
  const float* W3   = (const float*)d_in[18];
  const float* b3   = (const float*)d_in[19];
  const float* g1   = (const float*)d_in[20];
  const float* be1  = (const float*)d_in[21];
  const float* g2   = (const float*)d_in[22];
  const float* be2  = (const float*)d_in[23];
  float* out = (float*)d_out;
  float* wsf = (float*)d_ws;

  float* Wcat = wsf;                     // 442368
  float* proj = Wcat + 442368;           // 589824
  float* rotb = proj + 589824;           // 4608
  float* qpg  = rotb + 4608;             // 73728
  float* kpg  = qpg + 73728;             // 73728
  float* vpg  = kpg + 73728;             // 147456
  float* shid = vpg + 147456;            // 1867776
  float* cpart= shid + 1867776;          // 1179648
  float* C1   = cpart + 1179648;         // 196608
  float* s1   = C1 + 196608;             // 196608
  float* h1   = s1 + 196608;             // 196608
  float* h2   = h1 + 196608;             // 196608
  float* C3   = h2 + 196608;             // 196608

  concat_w_kernel<<<1728, 256, 0, stream>>>(Wq, Wk, Wv, Wqp, Wkp, Wvp, Wcat);
  gemm64_kernel<<<dim3(18, 8, 1), 256, 0, stream>>>(sfea, Wcat, proj, 512, 1152, 384, 384);
  frames_kernel<<<512, 64, 0, stream>>>(proj, quat, trsl, rotb, qpg, kpg, vpg);
  attn3_kernel<<<512, 768, 0, stream>>>(proj, qpg, kpg, vpg, pfea, Wb, rotb, trsl, scale, shid);

  gemm64_kernel<<<dim3(6, 8, 6), 256, 0, stream>>>(shid, Wsm, cpart, 512, 384, 3648, 608);
  reduce_kernel<<<768, 256, 0, stream>>>(cpart, C1, nullptr, 0, 196608, 384, 6);
  ln384_kernel<<<512, 384, 0, stream>>>(sfea, C1, bs, g1, be1, s1);

  gemm32_kernel<<<dim3(12, 16), 256, 0, stream>>>(s1, W1, b1, h1, 512, 384, 384, 1);
  gemm32_kernel<<<dim3(12, 16), 256, 0, stream>>>(h1, W2, b2, h2, 512, 384, 384, 1);
  gemm32_kernel<<<dim3(12, 16), 256, 0, stream>>>(h2, W3, nullptr, C3, 512, 384, 384, 0);
  ln384_kernel<<<512, 384, 0, stream>>>(s1, C3, b3, g2, be2, out);
}